// Round 7
// baseline (101.906 us; speedup 1.0000x reference)
//
#include <hip/hip_runtime.h>
#include <math.h>

#define N_PROP 1000
#define N_CLS  81
#define N_FG   80
#define SCORE_THRESH 0.05f
#define NMS_THRESH   0.5f
#define DET_PER_IMG  100
#define BBOX_CLIP    4.135166556742356f   // ln(1000/16)

// d_out layout (560000 floats):
//   [0, 400000)        out5: (80*1000, 5)
//   [400000, 480000)   labels as float
//   [480000, 560000)   final mask as 0.0/1.0
#define LBL_OFF    400000
#define FIN_OFF    480000

// ws layout (bytes):
//   [0,4)               int   survivor count
//   [4,8)               int   done counter (last-block flag)
//   [64, 320064)        float probT[80][1000]
//   [320064, 640064)    float compact survivor scores
//   [640064, 960064)    int   survivor row ids (c*1000+j)

// ---------------- K1: zero output + softmax -> probT (transposed) ----------
__global__ __launch_bounds__(256)
void softmax_zero_kernel(const float* __restrict__ logits,
                         float* __restrict__ out,
                         int* __restrict__ count,
                         int* __restrict__ done,
                         float* __restrict__ probT) {
    const int b = blockIdx.x;
    const int t = threadIdx.x;
    const int lane = t & 63;
    const int wave = t >> 6;
    if (b == 0 && t == 0) { *count = 0; *done = 0; }

    float4 z = make_float4(0.f, 0.f, 0.f, 0.f);
    float4* o4 = (float4*)out;
    for (int i = b * 256 + t; i < 140000; i += 250 * 256) o4[i] = z;

    const int n = b * 4 + wave;           // 250 blocks * 4 waves = 1000
    if (n < N_PROP) {
        const float* lrow = logits + (size_t)n * N_CLS;
        float v0 = lrow[lane];
        float v1 = (lane + 64 < N_CLS) ? lrow[lane + 64] : -INFINITY;
        float m = fmaxf(v0, v1);
        for (int off = 32; off; off >>= 1) m = fmaxf(m, __shfl_down(m, off));
        m = __shfl(m, 0);
        float e0 = expf(v0 - m);
        float e1 = (lane + 64 < N_CLS) ? expf(v1 - m) : 0.0f;
        float s = e0 + e1;
        for (int off = 32; off; off >>= 1) s += __shfl_down(s, off);
        s = __shfl(s, 0);
        if (lane >= 1)          probT[(size_t)(lane - 1) * N_PROP + n] = e0 / s;
        if (lane + 64 < N_CLS)  probT[(size_t)(lane + 63) * N_PROP + n] = e1 / s;
    }
}

__device__ __forceinline__ void decode_box(const float* __restrict__ props,
                                           const float* __restrict__ reg,
                                           int j, int cls, float W1, float H1,
                                           float& bx1, float& by1, float& bx2,
                                           float& by2, float& area) {
    float4 pr = *(const float4*)(props + (size_t)j * 4);
    float w  = pr.z - pr.x + 1.0f;
    float h  = pr.w - pr.y + 1.0f;
    float cx = pr.x + 0.5f * w;
    float cy = pr.y + 0.5f * h;
    float4 rr = *(const float4*)(reg + ((size_t)j * N_CLS + cls) * 4);
    float dx = rr.x / 10.0f;
    float dy = rr.y / 10.0f;
    float dw = fminf(rr.z / 5.0f, BBOX_CLIP);
    float dh = fminf(rr.w / 5.0f, BBOX_CLIP);
    float pcx = dx * w + cx;
    float pcy = dy * h + cy;
    float pw = expf(dw) * w;
    float ph = expf(dh) * h;
    bx1 = fminf(fmaxf(pcx - 0.5f * pw, 0.0f), W1);
    by1 = fminf(fmaxf(pcy - 0.5f * ph, 0.0f), H1);
    bx2 = fminf(fmaxf(pcx + 0.5f * pw - 1.0f, 0.0f), W1);
    by2 = fminf(fmaxf(pcy + 0.5f * ph - 1.0f, 0.0f), H1);
    area = (bx2 - bx1 + 1.0f) * (by2 - by1 + 1.0f);
}

// ---------------- K2: one wave per class, register NMS + last-block finalize
__global__ __launch_bounds__(64)
void nms_kernel(const float* __restrict__ probT,
                const float* __restrict__ props,
                const float* __restrict__ reg,
                const int* __restrict__ ihp,
                const int* __restrict__ iwp,
                float* __restrict__ out,
                int* __restrict__ count,
                int* __restrict__ done,
                float* __restrict__ compact,
                int* __restrict__ svRow) {
    const int c = blockIdx.x;       // 0..79
    const int lane = threadIdx.x;   // 0..63
    const int cls = c + 1;
    const unsigned long long lmask = (1ull << lane) - 1ull;

    __shared__ float2 sComp[N_PROP];   // (score, idx-as-float-bits)
    __shared__ float2 sSort[128];
    __shared__ float  sF[8192];        // fallback arrays / finalize staging

    const float W1 = (float)iwp[0] - 1.0f;
    const float H1 = (float)ihp[0] - 1.0f;

    // ---- phase 0: load scores (all loads issued up-front), ballot-compact ----
    float scv[16];
    #pragma unroll
    for (int it = 0; it < 16; ++it) {
        int j = it * 64 + lane;
        scv[it] = (j < N_PROP) ? probT[(size_t)c * N_PROP + j] : -1.0f;
    }
    int V = 0;
    #pragma unroll
    for (int it = 0; it < 16; ++it) {
        int j = it * 64 + lane;
        bool val = (j < N_PROP) && (scv[it] > SCORE_THRESH);
        unsigned long long mask = __ballot(val);
        if (val) sComp[V + __popcll(mask & lmask)] = make_float2(scv[it], __int_as_float(j));
        V += __popcll(mask);              // wave-uniform
    }
    __syncthreads();   // single wave: compiles to waitcnt, near-free

    if (V <= 128) {
        // ---- register path: 2 candidates per lane ----
        float s0 = -1.0f, s1 = -1.0f; int i0 = 0, i1 = 0;
        if (lane < V)      { float2 q = sComp[lane];      s0 = q.x; i0 = __float_as_int(q.y); }
        if (64 + lane < V) { float2 q = sComp[64 + lane]; s1 = q.x; i1 = __float_as_int(q.y); }

        // stable descending rank (ties -> lower original index)
        int r0 = 0, r1 = 0;
        for (int u = 0; u < V; ++u) {
            float2 q = sComp[u];
            float su = q.x; int iu = __float_as_int(q.y);
            r0 += (su > s0) || (su == s0 && iu < i0);
            r1 += (su > s1) || (su == s1 && iu < i1);
        }
        if (lane < V)      sSort[r0] = make_float2(s0, __int_as_float(i0));
        if (64 + lane < V) sSort[r1] = make_float2(s1, __int_as_float(i1));
        __syncthreads();

        // my sorted slots: rank `lane` (slot0) and rank `64+lane` (slot1)
        float sc0 = 0.f, sc1 = 0.f; int j0 = 0, j1 = 0;
        if (lane < V)      { float2 q = sSort[lane];      sc0 = q.x; j0 = __float_as_int(q.y); }
        if (64 + lane < V) { float2 q = sSort[64 + lane]; sc1 = q.x; j1 = __float_as_int(q.y); }

        float x10, y10, x20, y20, a0, x11, y11, x21, y21, a1;
        decode_box(props, reg, j0, cls, W1, H1, x10, y10, x20, y20, a0);
        decode_box(props, reg, j1, cls, W1, H1, x11, y11, x21, y21, a1);

        // greedy suppression: pure shuffle/ballot, no LDS, no barriers
        bool al0 = (lane < V), al1 = (64 + lane < V);
        unsigned long long am0 = __ballot(al0), am1 = __ballot(al1);
        for (int r = 0; r < V; ++r) {
            bool aliveR = (r < 64) ? ((am0 >> r) & 1ull) : ((am1 >> (r - 64)) & 1ull);
            if (!aliveR) continue;    // uniform branch
            float X1, Y1, X2, Y2, A;
            if (r < 64) {
                X1 = __shfl(x10, r); Y1 = __shfl(y10, r);
                X2 = __shfl(x20, r); Y2 = __shfl(y20, r); A = __shfl(a0, r);
            } else {
                X1 = __shfl(x11, r - 64); Y1 = __shfl(y11, r - 64);
                X2 = __shfl(x21, r - 64); Y2 = __shfl(y21, r - 64); A = __shfl(a1, r - 64);
            }
            if (al0 && lane > r) {
                float iw = fmaxf(fminf(X2, x20) - fmaxf(X1, x10) + 1.0f, 0.0f);
                float ih = fmaxf(fminf(Y2, y20) - fmaxf(Y1, y10) + 1.0f, 0.0f);
                float inter = iw * ih;
                float iou = inter / (A + a0 - inter);
                if (iou > NMS_THRESH) al0 = false;   // NaN-safe, like ref
            }
            if (al1 && 64 + lane > r) {
                float iw = fmaxf(fminf(X2, x21) - fmaxf(X1, x11) + 1.0f, 0.0f);
                float ih = fmaxf(fminf(Y2, y21) - fmaxf(Y1, y11) + 1.0f, 0.0f);
                float inter = iw * ih;
                float iou = inter / (A + a1 - inter);
                if (iou > NMS_THRESH) al1 = false;
            }
            am0 = __ballot(al0); am1 = __ballot(al1);
        }

        // survivor writes + single wave-aggregated atomic append
        int n0 = __popcll(am0), n1 = __popcll(am1);
        int base = 0;
        if (lane == 0 && (n0 + n1) > 0) base = atomicAdd(count, n0 + n1);
        base = __shfl(base, 0);
        if (al0) {
            int row = c * N_PROP + j0;
            size_t o = (size_t)row * 5;
            out[o + 0] = x10; out[o + 1] = y10; out[o + 2] = x20; out[o + 3] = y20; out[o + 4] = sc0;
            out[LBL_OFF + row] = (float)cls;
            out[FIN_OFF + row] = 1.0f;
            int pos = base + __popcll(am0 & lmask);
            compact[pos] = sc0; svRow[pos] = row;
        }
        if (al1) {
            int row = c * N_PROP + j1;
            size_t o = (size_t)row * 5;
            out[o + 0] = x11; out[o + 1] = y11; out[o + 2] = x21; out[o + 3] = y21; out[o + 4] = sc1;
            out[LBL_OFF + row] = (float)cls;
            out[FIN_OFF + row] = 1.0f;
            int pos = base + n0 + __popcll(am1 & lmask);
            compact[pos] = sc1; svRow[pos] = row;
        }
    } else {
        // ---- fallback (V > 128): proven LDS sequential path, single wave ----
        float* fx1 = sF;          float* fy1 = sF + 1000;
        float* fx2 = sF + 2000;   float* fy2 = sF + 3000;
        float* fa  = sF + 4000;   float* fs  = sF + 5000;
        int*   fj  = (int*)(sF + 6000);
        int*   fk  = (int*)(sF + 7000);
        for (int v = lane; v < V; v += 64) {
            float2 q = sComp[v];
            float s = q.x; int id = __float_as_int(q.y);
            int r = 0;
            for (int u = 0; u < V; ++u) {
                float2 qu = sComp[u];
                r += (qu.x > s) || (qu.x == s && __float_as_int(qu.y) < id);
            }
            float bx1, by1, bx2, by2, ar;
            decode_box(props, reg, id, cls, W1, H1, bx1, by1, bx2, by2, ar);
            fx1[r] = bx1; fy1[r] = by1; fx2[r] = bx2; fy2[r] = by2;
            fa[r] = ar; fs[r] = s; fj[r] = id; fk[r] = 1;
        }
        __syncthreads();
        for (int r = 0; r < V; ++r) {
            if (fk[r]) {
                const float X1 = fx1[r], Y1 = fy1[r], X2 = fx2[r], Y2 = fy2[r], A = fa[r];
                for (int v = r + 1 + lane; v < V; v += 64) {
                    if (fk[v]) {
                        float iw = fmaxf(fminf(X2, fx2[v]) - fmaxf(X1, fx1[v]) + 1.0f, 0.0f);
                        float ih = fmaxf(fminf(Y2, fy2[v]) - fmaxf(Y1, fy1[v]) + 1.0f, 0.0f);
                        float inter = iw * ih;
                        float iou = inter / (A + fa[v] - inter);
                        if (iou > NMS_THRESH) fk[v] = 0;
                    }
                }
            }
            __syncthreads();
        }
        for (int v = lane; v < V; v += 64) {
            if (fk[v]) {
                int row = c * N_PROP + fj[v];
                size_t o = (size_t)row * 5;
                out[o + 0] = fx1[v]; out[o + 1] = fy1[v]; out[o + 2] = fx2[v];
                out[o + 3] = fy2[v]; out[o + 4] = fs[v];
                out[LBL_OFF + row] = (float)cls;
                out[FIN_OFF + row] = 1.0f;
                int pos = atomicAdd(count, 1);
                compact[pos] = fs[v]; svRow[pos] = row;
            }
        }
        __syncthreads();
    }

    // ---- last-block finalize (single wave, shuffle-only reductions) ----
    __threadfence();
    int old = 0;
    if (lane == 0) old = __hip_atomic_fetch_add(done, 1, __ATOMIC_ACQ_REL, __HIP_MEMORY_SCOPE_AGENT);
    old = __shfl(old, 0);
    if (old != N_FG - 1) return;
    __threadfence();

    const int n = __hip_atomic_load(count, __ATOMIC_RELAXED, __HIP_MEMORY_SCOPE_AGENT);
    if (n <= DET_PER_IMG) return;   // th = 0 -> all survivors pass, nothing to fix

    const bool useL = (n <= 8192);
    if (useL) {
        for (int i = lane; i < n; i += 64)
            sF[i] = __hip_atomic_load(&compact[i], __ATOMIC_RELAXED, __HIP_MEMORY_SCOPE_AGENT);
        __syncthreads();
    }
    unsigned lo = 0x3D4CCCCCu, hi = 0x40000000u;   // scores in (0.05, 1.0]
    while (hi - lo > 1u) {
        unsigned mid = lo + ((hi - lo) >> 1);
        float mv = __uint_as_float(mid);
        int cnt = 0;
        if (useL) {
            for (int i = lane; i < n; i += 64) cnt += (sF[i] >= mv) ? 1 : 0;
        } else {
            for (int i = lane; i < n; i += 64)
                cnt += (__hip_atomic_load(&compact[i], __ATOMIC_RELAXED, __HIP_MEMORY_SCOPE_AGENT) >= mv) ? 1 : 0;
        }
        for (int off = 32; off; off >>= 1) cnt += __shfl_xor(cnt, off);
        if (cnt >= DET_PER_IMG + 1) lo = mid; else hi = mid;   // uniform
    }
    const float th = __uint_as_float(lo);

    for (int i = lane; i < n; i += 64) {
        float sc = useL ? sF[i]
                        : __hip_atomic_load(&compact[i], __ATOMIC_RELAXED, __HIP_MEMORY_SCOPE_AGENT);
        if (sc < th) {
            int row = __hip_atomic_load(&svRow[i], __ATOMIC_RELAXED, __HIP_MEMORY_SCOPE_AGENT);
            size_t o = (size_t)row * 5;
            out[o + 0] = 0.0f; out[o + 1] = 0.0f; out[o + 2] = 0.0f;
            out[o + 3] = 0.0f; out[o + 4] = 0.0f;
            out[LBL_OFF + row] = 0.0f;
            out[FIN_OFF + row] = 0.0f;
        }
    }
}

extern "C" void kernel_launch(void* const* d_in, const int* in_sizes, int n_in,
                              void* d_out, int out_size, void* d_ws, size_t ws_size,
                              hipStream_t stream) {
    const float* logits = (const float*)d_in[0];
    const float* reg    = (const float*)d_in[1];
    const float* props  = (const float*)d_in[2];
    const int*   ihp    = (const int*)d_in[3];
    const int*   iwp    = (const int*)d_in[4];
    float* out = (float*)d_out;

    char* ws = (char*)d_ws;
    int*   count   = (int*)(ws + 0);
    int*   done    = (int*)(ws + 4);
    float* probT   = (float*)(ws + 64);
    float* compact = (float*)(ws + 320064);
    int*   svRow   = (int*)(ws + 640064);

    softmax_zero_kernel<<<250, 256, 0, stream>>>(logits, out, count, done, probT);
    nms_kernel<<<N_FG, 64, 0, stream>>>(probT, props, reg, ihp, iwp,
                                        out, count, done, compact, svRow);
}